// Round 9
// baseline (425.902 us; speedup 1.0000x reference)
//
#include <hip/hip_runtime.h>
#include <math.h>

#define NPB 4096
#define BB 2
#define NN (NPB*BB)          // 8192
#define DIM 64
#define KK 5
#define NKR (NPB*KK)         // 20480
#define ET (BB*NKR)          // 40960 edges
#define SPLITS 16
#define RPS (NPB/SPLITS)     // 256 rows per split
#define NT8 (RPS/32)         // 8 mfma row-tiles per split

typedef __attribute__((ext_vector_type(8))) __bf16 bf16x8;
typedef __attribute__((ext_vector_type(16))) float f32x16;
typedef __attribute__((ext_vector_type(4))) unsigned u32x4;

__device__ __forceinline__ float clip_exp(const float* tptr) {
    return expf(fminf(fmaxf(tptr[0], -5.0f), 5.0f));
}

__device__ __forceinline__ unsigned enc_f(float f) {
    unsigned u = __float_as_uint(f);
    return (u & 0x80000000u) ? ~u : (u | 0x80000000u);
}
__device__ __forceinline__ float dec_f(unsigned e) {
    unsigned u = (e & 0x80000000u) ? (e ^ 0x80000000u) : ~e;
    return __uint_as_float(u);
}

// RNE float -> bf16 bits (finite inputs only)
__device__ __forceinline__ unsigned short f2bf(float f) {
    unsigned u = __float_as_uint(f);
    unsigned r = u + 0x7FFFu + ((u >> 16) & 1u);
    return (unsigned short)(r >> 16);
}

// branchless descending insert into top-8 (u32 packed keys; larger = closer)
__device__ __forceinline__ void insD8(unsigned (&d)[8], unsigned v) {
    bool c[8];
#pragma unroll
    for (int m = 0; m < 8; ++m) c[m] = v > d[m];
#pragma unroll
    for (int m = 7; m > 0; --m) d[m] = c[m - 1] ? d[m - 1] : (c[m] ? v : d[m]);
    d[0] = c[0] ? v : d[0];
}

// ascending lexicographic (d, idx) insert for exact re-rank
template<int NK>
__device__ __forceinline__ void insLex(float (&d)[NK], int (&ix)[NK], float dd, int ii) {
    bool c[NK];
#pragma unroll
    for (int m = 0; m < NK; ++m) c[m] = (dd < d[m]) || (dd == d[m] && ii < ix[m]);
    if (c[NK - 1]) {
#pragma unroll
        for (int m = NK - 1; m > 0; --m) {
            d[m]  = c[m - 1] ? d[m - 1]  : (c[m] ? dd : d[m]);
            ix[m] = c[m - 1] ? ix[m - 1] : (c[m] ? ii : ix[m]);
        }
        if (c[0]) { d[0] = dd; ix[0] = ii; }
    }
}

// ---------------- fused: pre_fc + embed1 + pq1 + acc-init
// block = 4 rows; wave = one row (64 channels). x0 lives in registers.
__global__ __launch_bounds__(256) void k_pre_all(const float* __restrict__ X,
        const float* __restrict__ Wpre, const float* __restrict__ bpre,
        const float* __restrict__ Wd1, const float* __restrict__ bd1,
        const float* __restrict__ Wc1, const float* __restrict__ bc1,
        float* __restrict__ ge, float* __restrict__ sqout,
        unsigned short* __restrict__ GH, unsigned short* __restrict__ GL,
        unsigned* __restrict__ SNH,
        float* __restrict__ P, float* __restrict__ Q, unsigned* __restrict__ acc) {
    int row = blockIdx.x * 4 + (threadIdx.x >> 6);
    int c = threadIdx.x & 63;
    const float* xr = X + (size_t)row * 32;
    float x0 = bpre[c];
#pragma unroll
    for (int d = 0; d < 32; ++d) x0 = fmaf(xr[d], Wpre[d * 64 + c], x0);
    x0 = x0 > 0.f ? x0 : 0.1f * x0;

    float ga = bd1[c], ap = bc1[c], aq = 0.f;
#pragma unroll 8
    for (int d = 0; d < 64; ++d) {
        float xv = __shfl(x0, d, 64);
        ga = fmaf(xv, Wd1[d * 64 + c], ga);
        float w1 = Wc1[(64 + d) * 64 + c];
        aq = fmaf(xv, w1, aq);
        ap = fmaf(xv, Wc1[d * 64 + c] - w1, ap);
    }
    size_t idx = (size_t)row * 64 + c;
    ge[idx] = ga; P[idx] = ap; Q[idx] = aq; acc[idx] = 0x007FFFFFu;
    unsigned short h = f2bf(ga);
    GH[idx] = h;
    GL[idx] = f2bf(ga - __uint_as_float((unsigned)h << 16));
    float s = ga * ga;
#pragma unroll
    for (int off = 32; off; off >>= 1) s += __shfl_xor(s, off, 64);
    if (c == 0) {
        sqout[row] = s;
        float ns2 = -0.5f * s;
        unsigned short nh = f2bf(ns2);
        unsigned short nl = f2bf(ns2 - __uint_as_float((unsigned)nh << 16));
        SNH[row] = (unsigned)nh | ((unsigned)nl << 16);
    }
}

// ---------------- fused: decode1 + embed2 + pq2 + acc-reinit
__global__ __launch_bounds__(256) void k_embed_dec(const float* __restrict__ ge1,
        const float* __restrict__ Wd2, const float* __restrict__ bd2,
        const float* __restrict__ Wc2, const float* __restrict__ bc2,
        float* __restrict__ P, float* __restrict__ Q, unsigned* __restrict__ acc,
        float* __restrict__ x1v, float* __restrict__ ge2, float* __restrict__ sqout,
        unsigned short* __restrict__ GH, unsigned short* __restrict__ GL,
        unsigned* __restrict__ SNH) {
    int row = blockIdx.x * 4 + (threadIdx.x >> 6);
    int c = threadIdx.x & 63;
    size_t idx = (size_t)row * 64 + c;
    float m = dec_f(acc[idx]);
    float x1 = (m == -INFINITY) ? 0.0f : fmaxf(m + P[idx], 0.0f);
    x1v[idx] = x1;
    const float* g1r = ge1 + (size_t)row * 64;
    float ga = bd2[c], ap = bc2[c], aq = 0.f;
#pragma unroll 8
    for (int d = 0; d < 64; ++d) {
        float gv = g1r[d];
        float xv = __shfl(x1, d, 64);
        ga = fmaf(gv, Wd2[d * 64 + c], ga);
        ga = fmaf(xv, Wd2[(64 + d) * 64 + c], ga);
        float w1 = Wc2[(64 + d) * 64 + c];
        aq = fmaf(xv, w1, aq);
        ap = fmaf(xv, Wc2[d * 64 + c] - w1, ap);
    }
    ge2[idx] = ga; P[idx] = ap; Q[idx] = aq; acc[idx] = 0x007FFFFFu;
    unsigned short h = f2bf(ga);
    GH[idx] = h;
    GL[idx] = f2bf(ga - __uint_as_float((unsigned)h << 16));
    float s = ga * ga;
#pragma unroll
    for (int off = 32; off; off >>= 1) s += __shfl_xor(s, off, 64);
    if (c == 0) {
        sqout[row] = s;
        float ns2 = -0.5f * s;
        unsigned short nh = f2bf(ns2);
        unsigned short nl = f2bf(ns2 - __uint_as_float((unsigned)nh << 16));
        SNH[row] = (unsigned)nh | ((unsigned)nl << 16);
    }
}

// ---------------- knn via MFMA with 4-row pooled top-8 selection.
// Groups = disjoint runs of 4 consecutive rows (= one reg-quad of the C frag).
// Guarantee: any true top-8 row's group-pool ranks <= 8 at split & global level,
// so global top-8 pooled groups (expanded x4 in k_select) contain true top-5.
__global__ __launch_bounds__(256, 4) void k_knn_mfma(
        const unsigned short* __restrict__ GH, const unsigned short* __restrict__ GL,
        const unsigned* __restrict__ SNH, unsigned* __restrict__ pk) {
    const int b_ = blockIdx.y, rs = blockIdx.z;
    const int w = threadIdx.x >> 6, lane = threadIdx.x & 63;
    const int half = lane >> 5, l31 = lane & 31;
    const int col = blockIdx.x * 128 + w * 32 + l31;
    const unsigned short* GHb = GH + (size_t)b_ * NPB * DIM;
    const unsigned short* GLb = GL + (size_t)b_ * NPB * DIM;
    const unsigned* SNHb = SNH + (size_t)b_ * NPB;

    bf16x8 Bh[4], Bl[4];
    {
        const size_t bro = (size_t)col * DIM + half * 8;
#pragma unroll
        for (int ks = 0; ks < 4; ++ks) {
            Bh[ks] = *(const bf16x8*)&GHb[bro + ks * 16];
            Bl[ks] = *(const bf16x8*)&GLb[bro + ks * 16];
        }
    }
    u32x4 bexu = {half ? 0u : 0x3F803F80u, 0u, 0u, 0u};
    bf16x8 Bex = *(bf16x8*)&bexu;

    unsigned t8[8];
#pragma unroll
    for (int m = 0; m < 8; ++m) t8[m] = 0u;

    const int r0 = rs * RPS;
    for (int tb = 0; tb < NT8; ++tb) {
        const int rbase = r0 + tb * 32;
        const size_t aro = (size_t)(rbase + l31) * DIM + half * 8;
        bf16x8 Ah[4], Al[4];
#pragma unroll
        for (int ks = 0; ks < 4; ++ks) {
            Ah[ks] = *(const bf16x8*)&GHb[aro + ks * 16];
            Al[ks] = *(const bf16x8*)&GLb[aro + ks * 16];
        }
        unsigned sn = SNHb[rbase + l31];
        u32x4 aexu = {half ? 0u : sn, 0u, 0u, 0u};
        bf16x8 Aex = *(bf16x8*)&aexu;

        f32x16 acc = {0,0,0,0,0,0,0,0,0,0,0,0,0,0,0,0};
        acc = __builtin_amdgcn_mfma_f32_32x32x16_bf16(Aex, Bex, acc, 0, 0, 0);
#pragma unroll
        for (int ks = 0; ks < 4; ++ks) {
            acc = __builtin_amdgcn_mfma_f32_32x32x16_bf16(Ah[ks], Bh[ks], acc, 0, 0, 0);
            acc = __builtin_amdgcn_mfma_f32_32x32x16_bf16(Ah[ks], Bl[ks], acc, 0, 0, 0);
            acc = __builtin_amdgcn_mfma_f32_32x32x16_bf16(Al[ks], Bh[ks], acc, 0, 0, 0);
        }
        // C: col=lane&31, row = rbase + (reg&3) + 8*(reg>>2) + 4*half
        // low 12 bits of key = ~row (ties prefer lower row). Quad qd = regs 4qd..4qd+3
        // covers rows rbase + 8qd + 4half + {0..3} (consecutive, 4-aligned).
        const unsigned Cb = (0xFFFu ^ (unsigned)(rbase & 0xFFF)) ^ (unsigned)(half << 2);
#pragma unroll
        for (int qd = 0; qd < 4; ++qd) {
            unsigned best = 0u;
#pragma unroll
            for (int r2 = 0; r2 < 4; ++r2) {
                const int reg = qd * 4 + r2;
                const unsigned brit = (unsigned)((reg & 3) + 8 * (reg >> 2));
                unsigned u = __float_as_uint(acc[reg]);
                unsigned e = u ^ ((unsigned)((int)u >> 31) | 0x80000000u);
                unsigned p = (e & 0xFFFFF000u) | (Cb ^ brit);
                best = best > p ? best : p;
            }
            insD8(t8, best);
        }
    }
    // merge halves (disjoint groups, same column)
    {
        unsigned o[8];
#pragma unroll
        for (int m = 0; m < 8; ++m)
            o[m] = (unsigned)__shfl_xor((int)t8[m], 32, 64);
#pragma unroll
        for (int m = 0; m < 8; ++m) insD8(t8, o[m]);
    }
    if (half == 0) {
        size_t base = (((size_t)(b_ * SPLITS + rs)) * NPB + col) * 8;
#pragma unroll
        for (int m = 0; m < 8; ++m) pk[base + m] = t8[m];
    }
}

// ---------------- select: merge SPLITS pooled lists -> top-8 groups,
// expand x4, exact fp32 re-rank -> stable top-5
__global__ __launch_bounds__(64) void k_select(const float* __restrict__ ge,
        const float* __restrict__ sq, const unsigned* __restrict__ pk,
        int* __restrict__ idxout) {
    int q = blockIdx.x * 64 + threadIdx.x;   // over BB*NPB
    int b_ = q >> 12, j = q & (NPB - 1);
    unsigned t8[8];
#pragma unroll
    for (int m = 0; m < 8; ++m) t8[m] = 0u;
    for (int rs = 0; rs < SPLITS; ++rs) {
        const unsigned* src = pk + (((size_t)(b_ * SPLITS + rs)) * NPB + j) * 8;
#pragma unroll
        for (int m = 0; m < 8; ++m) insD8(t8, src[m]);
    }
    const float* geb = ge + (size_t)b_ * NPB * DIM;
    const float* sqb = sq + (size_t)b_ * NPB;
    float4 gjv[16];
#pragma unroll
    for (int d4 = 0; d4 < 16; ++d4)
        gjv[d4] = *(const float4*)&geb[(size_t)j * DIM + d4 * 4];
    float sjv = sqb[j];
    float bd[KK]; int bi[KK];
#pragma unroll
    for (int m = 0; m < KK; ++m) { bd[m] = INFINITY; bi[m] = 0x7FFFFFFF; }
#pragma unroll
    for (int m = 0; m < 8; ++m) {
        int win = (int)((~t8[m]) & 0xFFFu);
        int g0 = win & ~3;
#pragma unroll
        for (int r = 0; r < 4; ++r) {
            int i = g0 + r;
            const float* gi = geb + (size_t)i * DIM;
            float dot = 0.f;
#pragma unroll
            for (int d4 = 0; d4 < 16; ++d4) {
                float4 g = *(const float4*)&gi[d4 * 4];
                dot = fmaf(g.x, gjv[d4].x, dot);
                dot = fmaf(g.y, gjv[d4].y, dot);
                dot = fmaf(g.z, gjv[d4].z, dot);
                dot = fmaf(g.w, gjv[d4].w, dot);
            }
            float md = fmaxf(sqb[i] + sjv - 2.0f * dot, 0.0f);
            insLex<KK>(bd, bi, md, i);
        }
    }
    int* o = idxout + (size_t)q * KK;
#pragma unroll
    for (int m = 0; m < KK; ++m) o[m] = bi[m];
}

// faithful scrambled-reshape edge value: g in [0, 2*ET)
__device__ __forceinline__ int edge_val(const int* __restrict__ idx, int g) {
    int r = g >> 2;
    int rem = g & 3;
    int b_ = rem >> 1;
    if (rem & 1) return r / KK + b_ * NPB;               // centers (node-major)
    int j = r & (NPB - 1), k = r >> 12;                  // flat (k-major)
    return idx[(size_t)(b_ * NPB + j) * KK + k] + b_ * NPB;
}

// logprobs + edge arrays (float4 gathers)
__global__ __launch_bounds__(256) void k_lp_edges(const float* __restrict__ ge,
        const int* __restrict__ idx, const float* __restrict__ tptr,
        float* __restrict__ lp_out, int* __restrict__ e_src, int* __restrict__ e_dst) {
    int q = blockIdx.x * 256 + threadIdx.x;
    if (q >= ET) return;
    float t = clip_exp(tptr);
    int b_ = q / NKR;
    int r  = q - b_ * NKR;
    int fl = idx[(size_t)(b_ * NPB + (r & (NPB - 1))) * KK + (r >> 12)];
    int i  = r / KK;
    const float4* ga = (const float4*)(ge + (size_t)(b_ * NPB + fl) * DIM);
    const float4* gb = (const float4*)(ge + (size_t)(b_ * NPB + i) * DIM);
    float s = 0.f;
#pragma unroll
    for (int d4 = 0; d4 < 16; ++d4) {
        float4 a = ga[d4], b = gb[d4];
        float dx = a.x - b.x, dy = a.y - b.y, dz = a.z - b.z, dw = a.w - b.w;
        s = fmaf(dx, dx, s); s = fmaf(dy, dy, s);
        s = fmaf(dz, dz, s); s = fmaf(dw, dw, s);
    }
    lp_out[(size_t)q * 2] = -s * t;
    e_src[q] = edge_val(idx, q);
    e_dst[q] = edge_val(idx, q + ET);
}

// scatter: acc[dst][ch] = max(acc, Q[src][ch])
__global__ __launch_bounds__(256) void k_scatter(const float* __restrict__ Q,
        const int* __restrict__ esrc, const int* __restrict__ edst,
        unsigned* __restrict__ acc) {
    int idx = blockIdx.x * 256 + threadIdx.x;
    int e = idx >> 6, ch = idx & 63;
    int s = esrc[e], d = edst[e];
    atomicMax(&acc[(size_t)d * DIM + ch], enc_f(Q[(size_t)s * DIM + ch]));
}

// ---------------- fused: decode2 + fc -> out
__global__ __launch_bounds__(256) void k_dec_final(const unsigned* __restrict__ acc,
        const float* __restrict__ P,
        const float* __restrict__ Wf1, const float* __restrict__ bf1,
        const float* __restrict__ Wf2, const float* __restrict__ bf2,
        float* __restrict__ out) {
    int i = blockIdx.x * 256 + threadIdx.x;
    const uint4* ar = (const uint4*)(acc + (size_t)i * 64);
    const float4* pr = (const float4*)(P + (size_t)i * 64);
    float xv[DIM];
#pragma unroll
    for (int d4 = 0; d4 < 16; ++d4) {
        uint4 a = ar[d4]; float4 p = pr[d4];
        float m0 = dec_f(a.x), m1 = dec_f(a.y), m2 = dec_f(a.z), m3 = dec_f(a.w);
        xv[d4 * 4 + 0] = (m0 == -INFINITY) ? 0.f : fmaxf(m0 + p.x, 0.f);
        xv[d4 * 4 + 1] = (m1 == -INFINITY) ? 0.f : fmaxf(m1 + p.y, 0.f);
        xv[d4 * 4 + 2] = (m2 == -INFINITY) ? 0.f : fmaxf(m2 + p.z, 0.f);
        xv[d4 * 4 + 3] = (m3 == -INFINITY) ? 0.f : fmaxf(m3 + p.w, 0.f);
    }
    float h[32];
#pragma unroll
    for (int c = 0; c < 32; ++c) {
        float a = bf1[c];
#pragma unroll
        for (int d = 0; d < DIM; ++d) a = fmaf(xv[d], Wf1[d * 32 + c], a);
        h[c] = a > 0.f ? a : 0.1f * a;
    }
#pragma unroll
    for (int o8 = 0; o8 < 8; ++o8) {
        float a = bf2[o8];
#pragma unroll
        for (int c = 0; c < 32; ++c) a = fmaf(h[c], Wf2[c * 8 + o8], a);
        out[(size_t)i * 8 + o8] = a;
    }
}

extern "C" void kernel_launch(void* const* d_in, const int* in_sizes, int n_in,
                              void* d_out, int out_size, void* d_ws, size_t ws_size,
                              hipStream_t stream) {
    const float* x    = (const float*)d_in[0];
    const float* Wpre = (const float*)d_in[1];
    const float* bpre = (const float*)d_in[2];
    const float* Wd1  = (const float*)d_in[3];
    const float* bd1  = (const float*)d_in[4];
    const float* t1   = (const float*)d_in[5];
    const float* Wc1  = (const float*)d_in[6];
    const float* bc1  = (const float*)d_in[7];
    const float* Wd2  = (const float*)d_in[8];
    const float* bd2  = (const float*)d_in[9];
    const float* t2   = (const float*)d_in[10];
    const float* Wc2  = (const float*)d_in[11];
    const float* bc2  = (const float*)d_in[12];
    const float* Wf1  = (const float*)d_in[13];
    const float* bf1  = (const float*)d_in[14];
    const float* Wf2  = (const float*)d_in[15];
    const float* bf2  = (const float*)d_in[16];

    float* ws = (float*)d_ws;
    float* ge1  = ws;
    float* ge2  = ge1 + (size_t)NN * DIM;
    float* x1v  = ge2 + (size_t)NN * DIM;
    float* Pb   = x1v + (size_t)NN * DIM;
    float* Qb   = Pb  + (size_t)NN * DIM;
    float* sqv  = Qb  + (size_t)NN * DIM;
    unsigned* pk = (unsigned*)(sqv + NN);
    int*   idx1 = (int*)(pk + (size_t)BB * SPLITS * NPB * 8);
    int*   idx2 = idx1 + (size_t)BB * NPB * KK;
    int*   es1  = idx2 + (size_t)BB * NPB * KK;
    int*   ed1  = es1 + ET;
    int*   es2  = ed1 + ET;
    int*   ed2  = es2 + ET;
    unsigned* accb = (unsigned*)(ed2 + ET);
    unsigned short* geh = (unsigned short*)(accb + (size_t)NN * DIM);
    unsigned short* gel = geh + (size_t)NN * DIM;
    unsigned* snh = (unsigned*)(gel + (size_t)NN * DIM);

    float* outp = (float*)d_out;
    float* lpp  = outp + (size_t)NN * 8;

    dim3 blk(256);
    dim3 kgrid(NPB / 128, BB, SPLITS);

    k_pre_all<<<NN / 4, blk, 0, stream>>>(x, Wpre, bpre, Wd1, bd1, Wc1, bc1,
                                          ge1, sqv, geh, gel, snh, Pb, Qb, accb);
    k_knn_mfma<<<kgrid, blk, 0, stream>>>(geh, gel, snh, pk);
    k_select<<<(BB * NPB) / 64, dim3(64), 0, stream>>>(ge1, sqv, pk, idx1);
    k_lp_edges<<<ET / 256, blk, 0, stream>>>(ge1, idx1, t1, lpp + 0, es1, ed1);
    k_scatter<<<(ET * 64) / 256, blk, 0, stream>>>(Qb, es1, ed1, accb);
    k_embed_dec<<<NN / 4, blk, 0, stream>>>(ge1, Wd2, bd2, Wc2, bc2,
                                            Pb, Qb, accb, x1v, ge2, sqv, geh, gel, snh);
    k_knn_mfma<<<kgrid, blk, 0, stream>>>(geh, gel, snh, pk);
    k_select<<<(BB * NPB) / 64, dim3(64), 0, stream>>>(ge2, sqv, pk, idx2);
    k_lp_edges<<<ET / 256, blk, 0, stream>>>(ge2, idx2, t2, lpp + 1, es2, ed2);
    k_scatter<<<(ET * 64) / 256, blk, 0, stream>>>(Qb, es2, ed2, accb);
    k_dec_final<<<NN / 256, blk, 0, stream>>>(accb, Pb, Wf1, bf1, Wf2, bf2, outp);
}

// Round 10
// 272.723 us; speedup vs baseline: 1.5617x; 1.5617x over previous
//
#include <hip/hip_runtime.h>
#include <math.h>

#define NPB 4096
#define BB 2
#define NN (NPB*BB)          // 8192
#define DIM 64
#define KK 5
#define NKR (NPB*KK)         // 20480
#define ET (BB*NKR)          // 40960 edges
#define SPLITS 16
#define RPS (NPB/SPLITS)     // 256 rows per split
#define NT8 (RPS/32)         // 8 mfma row-tiles per split

typedef __attribute__((ext_vector_type(8))) __bf16 bf16x8;
typedef __attribute__((ext_vector_type(16))) float f32x16;
typedef __attribute__((ext_vector_type(4))) unsigned u32x4;

__device__ __forceinline__ float clip_exp(const float* tptr) {
    return expf(fminf(fmaxf(tptr[0], -5.0f), 5.0f));
}

__device__ __forceinline__ unsigned enc_f(float f) {
    unsigned u = __float_as_uint(f);
    return (u & 0x80000000u) ? ~u : (u | 0x80000000u);
}
__device__ __forceinline__ float dec_f(unsigned e) {
    unsigned u = (e & 0x80000000u) ? (e ^ 0x80000000u) : ~e;
    return __uint_as_float(u);
}

// RNE float -> bf16 bits (finite inputs only)
__device__ __forceinline__ unsigned short f2bf(float f) {
    unsigned u = __float_as_uint(f);
    unsigned r = u + 0x7FFFu + ((u >> 16) & 1u);
    return (unsigned short)(r >> 16);
}

// branchless descending insert into top-8 (u32 packed keys; larger = closer)
__device__ __forceinline__ void insD8(unsigned (&d)[8], unsigned v) {
    bool c[8];
#pragma unroll
    for (int m = 0; m < 8; ++m) c[m] = v > d[m];
#pragma unroll
    for (int m = 7; m > 0; --m) d[m] = c[m - 1] ? d[m - 1] : (c[m] ? v : d[m]);
    d[0] = c[0] ? v : d[0];
}

// ---------------- fused: pre_fc + embed1 + pq1 + acc-init
// block = 4 rows; wave = one row (64 channels). x0 lives in registers.
__global__ __launch_bounds__(256) void k_pre_all(const float* __restrict__ X,
        const float* __restrict__ Wpre, const float* __restrict__ bpre,
        const float* __restrict__ Wd1, const float* __restrict__ bd1,
        const float* __restrict__ Wc1, const float* __restrict__ bc1,
        float* __restrict__ ge, float* __restrict__ sqout,
        unsigned short* __restrict__ GH, unsigned short* __restrict__ GL,
        unsigned* __restrict__ SNH,
        float* __restrict__ P, float* __restrict__ Q, unsigned* __restrict__ acc) {
    int row = blockIdx.x * 4 + (threadIdx.x >> 6);
    int c = threadIdx.x & 63;
    const float* xr = X + (size_t)row * 32;
    float x0 = bpre[c];
#pragma unroll
    for (int d = 0; d < 32; ++d) x0 = fmaf(xr[d], Wpre[d * 64 + c], x0);
    x0 = x0 > 0.f ? x0 : 0.1f * x0;

    float ga = bd1[c], ap = bc1[c], aq = 0.f;
#pragma unroll 8
    for (int d = 0; d < 64; ++d) {
        float xv = __shfl(x0, d, 64);
        ga = fmaf(xv, Wd1[d * 64 + c], ga);
        float w1 = Wc1[(64 + d) * 64 + c];
        aq = fmaf(xv, w1, aq);
        ap = fmaf(xv, Wc1[d * 64 + c] - w1, ap);
    }
    size_t idx = (size_t)row * 64 + c;
    ge[idx] = ga; P[idx] = ap; Q[idx] = aq; acc[idx] = 0x007FFFFFu;
    unsigned short h = f2bf(ga);
    GH[idx] = h;
    GL[idx] = f2bf(ga - __uint_as_float((unsigned)h << 16));
    float s = ga * ga;
#pragma unroll
    for (int off = 32; off; off >>= 1) s += __shfl_xor(s, off, 64);
    if (c == 0) {
        sqout[row] = s;
        float ns2 = -0.5f * s;
        unsigned short nh = f2bf(ns2);
        unsigned short nl = f2bf(ns2 - __uint_as_float((unsigned)nh << 16));
        SNH[row] = (unsigned)nh | ((unsigned)nl << 16);
    }
}

// ---------------- fused: decode1 + embed2 + pq2 + acc-reinit
__global__ __launch_bounds__(256) void k_embed_dec(const float* __restrict__ ge1,
        const float* __restrict__ Wd2, const float* __restrict__ bd2,
        const float* __restrict__ Wc2, const float* __restrict__ bc2,
        float* __restrict__ P, float* __restrict__ Q, unsigned* __restrict__ acc,
        float* __restrict__ x1v, float* __restrict__ ge2, float* __restrict__ sqout,
        unsigned short* __restrict__ GH, unsigned short* __restrict__ GL,
        unsigned* __restrict__ SNH) {
    int row = blockIdx.x * 4 + (threadIdx.x >> 6);
    int c = threadIdx.x & 63;
    size_t idx = (size_t)row * 64 + c;
    float m = dec_f(acc[idx]);
    float x1 = (m == -INFINITY) ? 0.0f : fmaxf(m + P[idx], 0.0f);
    x1v[idx] = x1;
    const float* g1r = ge1 + (size_t)row * 64;
    float ga = bd2[c], ap = bc2[c], aq = 0.f;
#pragma unroll 8
    for (int d = 0; d < 64; ++d) {
        float gv = g1r[d];
        float xv = __shfl(x1, d, 64);
        ga = fmaf(gv, Wd2[d * 64 + c], ga);
        ga = fmaf(xv, Wd2[(64 + d) * 64 + c], ga);
        float w1 = Wc2[(64 + d) * 64 + c];
        aq = fmaf(xv, w1, aq);
        ap = fmaf(xv, Wc2[d * 64 + c] - w1, ap);
    }
    ge2[idx] = ga; P[idx] = ap; Q[idx] = aq; acc[idx] = 0x007FFFFFu;
    unsigned short h = f2bf(ga);
    GH[idx] = h;
    GL[idx] = f2bf(ga - __uint_as_float((unsigned)h << 16));
    float s = ga * ga;
#pragma unroll
    for (int off = 32; off; off >>= 1) s += __shfl_xor(s, off, 64);
    if (c == 0) {
        sqout[row] = s;
        float ns2 = -0.5f * s;
        unsigned short nh = f2bf(ns2);
        unsigned short nl = f2bf(ns2 - __uint_as_float((unsigned)nh << 16));
        SNH[row] = (unsigned)nh | ((unsigned)nl << 16);
    }
}

// ---------------- knn via MFMA with 4-row pooled top-8 selection.
// Groups = disjoint runs of 4 consecutive rows (= one reg-quad of the C frag).
// Any true top-8 row's group-pool ranks <= 8 at split & global level, so the
// global top-8 pooled groups (expanded x4 in k_select) contain the true top-5.
__global__ __launch_bounds__(256, 4) void k_knn_mfma(
        const unsigned short* __restrict__ GH, const unsigned short* __restrict__ GL,
        const unsigned* __restrict__ SNH, unsigned* __restrict__ pk) {
    const int b_ = blockIdx.y, rs = blockIdx.z;
    const int w = threadIdx.x >> 6, lane = threadIdx.x & 63;
    const int half = lane >> 5, l31 = lane & 31;
    const int col = blockIdx.x * 128 + w * 32 + l31;
    const unsigned short* GHb = GH + (size_t)b_ * NPB * DIM;
    const unsigned short* GLb = GL + (size_t)b_ * NPB * DIM;
    const unsigned* SNHb = SNH + (size_t)b_ * NPB;

    bf16x8 Bh[4], Bl[4];
    {
        const size_t bro = (size_t)col * DIM + half * 8;
#pragma unroll
        for (int ks = 0; ks < 4; ++ks) {
            Bh[ks] = *(const bf16x8*)&GHb[bro + ks * 16];
            Bl[ks] = *(const bf16x8*)&GLb[bro + ks * 16];
        }
    }
    u32x4 bexu = {half ? 0u : 0x3F803F80u, 0u, 0u, 0u};
    bf16x8 Bex = *(bf16x8*)&bexu;

    unsigned t8[8];
#pragma unroll
    for (int m = 0; m < 8; ++m) t8[m] = 0u;

    const int r0 = rs * RPS;
    for (int tb = 0; tb < NT8; ++tb) {
        const int rbase = r0 + tb * 32;
        const size_t aro = (size_t)(rbase + l31) * DIM + half * 8;
        bf16x8 Ah[4], Al[4];
#pragma unroll
        for (int ks = 0; ks < 4; ++ks) {
            Ah[ks] = *(const bf16x8*)&GHb[aro + ks * 16];
            Al[ks] = *(const bf16x8*)&GLb[aro + ks * 16];
        }
        unsigned sn = SNHb[rbase + l31];
        u32x4 aexu = {half ? 0u : sn, 0u, 0u, 0u};
        bf16x8 Aex = *(bf16x8*)&aexu;

        f32x16 acc = {0,0,0,0,0,0,0,0,0,0,0,0,0,0,0,0};
        acc = __builtin_amdgcn_mfma_f32_32x32x16_bf16(Aex, Bex, acc, 0, 0, 0);
#pragma unroll
        for (int ks = 0; ks < 4; ++ks) {
            acc = __builtin_amdgcn_mfma_f32_32x32x16_bf16(Ah[ks], Bh[ks], acc, 0, 0, 0);
            acc = __builtin_amdgcn_mfma_f32_32x32x16_bf16(Ah[ks], Bl[ks], acc, 0, 0, 0);
            acc = __builtin_amdgcn_mfma_f32_32x32x16_bf16(Al[ks], Bh[ks], acc, 0, 0, 0);
        }
        // C: col=lane&31, row = rbase + (reg&3) + 8*(reg>>2) + 4*half
        const unsigned Cb = (0xFFFu ^ (unsigned)(rbase & 0xFFF)) ^ (unsigned)(half << 2);
#pragma unroll
        for (int qd = 0; qd < 4; ++qd) {
            unsigned best = 0u;
#pragma unroll
            for (int r2 = 0; r2 < 4; ++r2) {
                const int reg = qd * 4 + r2;
                const unsigned brit = (unsigned)((reg & 3) + 8 * (reg >> 2));
                unsigned u = __float_as_uint(acc[reg]);
                unsigned e = u ^ ((unsigned)((int)u >> 31) | 0x80000000u);
                unsigned p = (e & 0xFFFFF000u) | (Cb ^ brit);
                best = best > p ? best : p;
            }
            insD8(t8, best);
        }
    }
    // merge halves (disjoint groups, same column)
    {
        unsigned o[8];
#pragma unroll
        for (int m = 0; m < 8; ++m)
            o[m] = (unsigned)__shfl_xor((int)t8[m], 32, 64);
#pragma unroll
        for (int m = 0; m < 8; ++m) insD8(t8, o[m]);
    }
    if (half == 0) {
        size_t base = (((size_t)(b_ * SPLITS + rs)) * NPB + col) * 8;
#pragma unroll
        for (int m = 0; m < 8; ++m) pk[base + m] = t8[m];
    }
}

// ---------------- select: one WAVE per column. Merge 16x8 pooled keys via
// 8x wave-max extraction (keys distinct by construction), expand top-8 groups
// to 32 candidates (one per lane), exact fp32 re-rank, stable top-5 via
// 5x (min-md reduce, then min-idx among ties).
__global__ __launch_bounds__(256) void k_select(const float* __restrict__ ge,
        const float* __restrict__ sq, const unsigned* __restrict__ pk,
        int* __restrict__ idxout) {
    const int w = threadIdx.x >> 6, lane = threadIdx.x & 63;
    const int q = blockIdx.x * 4 + w;          // over BB*NPB
    const int b_ = q >> 12, j = q & (NPB - 1);
    // phase 1: lane holds 2 of the 128 keys (split = lane>>2, pos = (lane&3)*2)
    const unsigned* src = pk +
        (((size_t)(b_ * SPLITS + (lane >> 2))) * NPB + j) * 8 + (lane & 3) * 2;
    unsigned k0 = src[0], k1 = src[1];
    unsigned t8[8];
#pragma unroll
    for (int it = 0; it < 8; ++it) {
        unsigned v = k0 > k1 ? k0 : k1;
        unsigned m = v;
#pragma unroll
        for (int off = 1; off < 64; off <<= 1) {
            unsigned o = (unsigned)__shfl_xor((int)m, off, 64);
            m = m > o ? m : o;
        }
        unsigned long long msk = __ballot(v == m);
        int first = (int)__ffsll(msk) - 1;
        if (lane == first) { if (k0 == m) k0 = 0u; else k1 = 0u; }
        t8[it] = m;
    }
    // phase 2: lane<32 computes exact md for candidate row i
    const float* geb = ge + (size_t)b_ * NPB * DIM;
    const float* sqb = sq + (size_t)b_ * NPB;
    int i = 0x7FFFFFFF;
    float md = INFINITY;
    if (lane < 32) {
        int g0 = ((int)((~t8[lane >> 2]) & 0xFFFu)) & ~3;
        i = g0 + (lane & 3);
        const float4* gi = (const float4*)(geb + (size_t)i * DIM);
        const float4* gj = (const float4*)(geb + (size_t)j * DIM);
        float dot = 0.f;
#pragma unroll
        for (int d4 = 0; d4 < 16; ++d4) {
            float4 a = gi[d4], b = gj[d4];
            dot = fmaf(a.x, b.x, dot); dot = fmaf(a.y, b.y, dot);
            dot = fmaf(a.z, b.z, dot); dot = fmaf(a.w, b.w, dot);
        }
        md = fmaxf(sqb[i] + sqb[j] - 2.0f * dot, 0.0f);
    }
    // phase 3: stable top-5 (min md, tie -> min idx)
    int* o = idxout + (size_t)q * KK;
#pragma unroll
    for (int it = 0; it < KK; ++it) {
        float mv = md;
#pragma unroll
        for (int off = 1; off < 64; off <<= 1)
            mv = fminf(mv, __shfl_xor(mv, off, 64));
        int ii = (md == mv) ? i : 0x7FFFFFFF;
#pragma unroll
        for (int off = 1; off < 64; off <<= 1) {
            int oi = __shfl_xor(ii, off, 64);
            ii = ii < oi ? ii : oi;
        }
        if (lane == 0) o[it] = ii;
        if (md == mv && i == ii) md = INFINITY;
    }
}

// faithful scrambled-reshape edge value: g in [0, 2*ET)
__device__ __forceinline__ int edge_val(const int* __restrict__ idx, int g) {
    int r = g >> 2;
    int rem = g & 3;
    int b_ = rem >> 1;
    if (rem & 1) return r / KK + b_ * NPB;               // centers (node-major)
    int j = r & (NPB - 1), k = r >> 12;                  // flat (k-major)
    return idx[(size_t)(b_ * NPB + j) * KK + k] + b_ * NPB;
}

// logprobs + edge arrays (float4 gathers)
__global__ __launch_bounds__(256) void k_lp_edges(const float* __restrict__ ge,
        const int* __restrict__ idx, const float* __restrict__ tptr,
        float* __restrict__ lp_out, int* __restrict__ e_src, int* __restrict__ e_dst) {
    int q = blockIdx.x * 256 + threadIdx.x;
    if (q >= ET) return;
    float t = clip_exp(tptr);
    int b_ = q / NKR;
    int r  = q - b_ * NKR;
    int fl = idx[(size_t)(b_ * NPB + (r & (NPB - 1))) * KK + (r >> 12)];
    int i  = r / KK;
    const float4* ga = (const float4*)(ge + (size_t)(b_ * NPB + fl) * DIM);
    const float4* gb = (const float4*)(ge + (size_t)(b_ * NPB + i) * DIM);
    float s = 0.f;
#pragma unroll
    for (int d4 = 0; d4 < 16; ++d4) {
        float4 a = ga[d4], b = gb[d4];
        float dx = a.x - b.x, dy = a.y - b.y, dz = a.z - b.z, dw = a.w - b.w;
        s = fmaf(dx, dx, s); s = fmaf(dy, dy, s);
        s = fmaf(dz, dz, s); s = fmaf(dw, dw, s);
    }
    lp_out[(size_t)q * 2] = -s * t;
    e_src[q] = edge_val(idx, q);
    e_dst[q] = edge_val(idx, q + ET);
}

// scatter: acc[dst][ch] = max(acc, Q[src][ch])
__global__ __launch_bounds__(256) void k_scatter(const float* __restrict__ Q,
        const int* __restrict__ esrc, const int* __restrict__ edst,
        unsigned* __restrict__ acc) {
    int idx = blockIdx.x * 256 + threadIdx.x;
    int e = idx >> 6, ch = idx & 63;
    int s = esrc[e], d = edst[e];
    atomicMax(&acc[(size_t)d * DIM + ch], enc_f(Q[(size_t)s * DIM + ch]));
}

// ---------------- fused: decode2 + fc -> out  (wave per row, lane = channel)
__global__ __launch_bounds__(256) void k_dec_final(const unsigned* __restrict__ acc,
        const float* __restrict__ P,
        const float* __restrict__ Wf1, const float* __restrict__ bf1,
        const float* __restrict__ Wf2, const float* __restrict__ bf2,
        float* __restrict__ out) {
    int row = blockIdx.x * 4 + (threadIdx.x >> 6);
    int c = threadIdx.x & 63;
    size_t idx = (size_t)row * 64 + c;
    float m = dec_f(acc[idx]);
    float xv = (m == -INFINITY) ? 0.f : fmaxf(m + P[idx], 0.f);
    // h for lanes c<32: bf1[c] + sum_d shfl(xv,d)*Wf1[d][c]
    float h = (c < 32) ? bf1[c & 31] : 0.f;
#pragma unroll 8
    for (int d = 0; d < 64; ++d) {
        float xd = __shfl(xv, d, 64);
        h = fmaf(xd, Wf1[d * 32 + (c & 31)], h);
    }
    h = (c < 32) ? (h > 0.f ? h : 0.1f * h) : 0.f;
    // out: lanes c<8 accumulate over the 32 h lanes
    float oa = (c < 8) ? bf2[c & 7] : 0.f;
#pragma unroll 8
    for (int cc = 0; cc < 32; ++cc) {
        float hc = __shfl(h, cc, 64);
        oa = fmaf(hc, Wf2[cc * 8 + (c & 7)], oa);
    }
    if (c < 8) out[(size_t)row * 8 + c] = oa;
}

extern "C" void kernel_launch(void* const* d_in, const int* in_sizes, int n_in,
                              void* d_out, int out_size, void* d_ws, size_t ws_size,
                              hipStream_t stream) {
    const float* x    = (const float*)d_in[0];
    const float* Wpre = (const float*)d_in[1];
    const float* bpre = (const float*)d_in[2];
    const float* Wd1  = (const float*)d_in[3];
    const float* bd1  = (const float*)d_in[4];
    const float* t1   = (const float*)d_in[5];
    const float* Wc1  = (const float*)d_in[6];
    const float* bc1  = (const float*)d_in[7];
    const float* Wd2  = (const float*)d_in[8];
    const float* bd2  = (const float*)d_in[9];
    const float* t2   = (const float*)d_in[10];
    const float* Wc2  = (const float*)d_in[11];
    const float* bc2  = (const float*)d_in[12];
    const float* Wf1  = (const float*)d_in[13];
    const float* bf1  = (const float*)d_in[14];
    const float* Wf2  = (const float*)d_in[15];
    const float* bf2  = (const float*)d_in[16];

    float* ws = (float*)d_ws;
    float* ge1  = ws;
    float* ge2  = ge1 + (size_t)NN * DIM;
    float* x1v  = ge2 + (size_t)NN * DIM;
    float* Pb   = x1v + (size_t)NN * DIM;
    float* Qb   = Pb  + (size_t)NN * DIM;
    float* sqv  = Qb  + (size_t)NN * DIM;
    unsigned* pk = (unsigned*)(sqv + NN);
    int*   idx1 = (int*)(pk + (size_t)BB * SPLITS * NPB * 8);
    int*   idx2 = idx1 + (size_t)BB * NPB * KK;
    int*   es1  = idx2 + (size_t)BB * NPB * KK;
    int*   ed1  = es1 + ET;
    int*   es2  = ed1 + ET;
    int*   ed2  = es2 + ET;
    unsigned* accb = (unsigned*)(ed2 + ET);
    unsigned short* geh = (unsigned short*)(accb + (size_t)NN * DIM);
    unsigned short* gel = geh + (size_t)NN * DIM;
    unsigned* snh = (unsigned*)(gel + (size_t)NN * DIM);

    float* outp = (float*)d_out;
    float* lpp  = outp + (size_t)NN * 8;

    dim3 blk(256);
    dim3 kgrid(NPB / 128, BB, SPLITS);

    k_pre_all<<<NN / 4, blk, 0, stream>>>(x, Wpre, bpre, Wd1, bd1, Wc1, bc1,
                                          ge1, sqv, geh, gel, snh, Pb, Qb, accb);
    k_knn_mfma<<<kgrid, blk, 0, stream>>>(geh, gel, snh, pk);
    k_select<<<(BB * NPB) / 4, blk, 0, stream>>>(ge1, sqv, pk, idx1);
    k_lp_edges<<<ET / 256, blk, 0, stream>>>(ge1, idx1, t1, lpp + 0, es1, ed1);
    k_scatter<<<(ET * 64) / 256, blk, 0, stream>>>(Qb, es1, ed1, accb);
    k_embed_dec<<<NN / 4, blk, 0, stream>>>(ge1, Wd2, bd2, Wc2, bc2,
                                            Pb, Qb, accb, x1v, ge2, sqv, geh, gel, snh);
    k_knn_mfma<<<kgrid, blk, 0, stream>>>(geh, gel, snh, pk);
    k_select<<<(BB * NPB) / 4, blk, 0, stream>>>(ge2, sqv, pk, idx2);
    k_lp_edges<<<ET / 256, blk, 0, stream>>>(ge2, idx2, t2, lpp + 1, es2, ed2);
    k_scatter<<<(ET * 64) / 256, blk, 0, stream>>>(Qb, es2, ed2, accb);
    k_dec_final<<<NN / 256, blk, 0, stream>>>(accb, Pb, Wf1, bf1, Wf2, bf2, outp);
}